// Round 1
// baseline (35993.777 us; speedup 1.0000x reference)
//
#include <hip/hip_runtime.h>
#include <math.h>

// Problem constants
#define BATCH   8192
#define EXP_DIM 1024
#define DICT    4096
#define NIT     20
#define KSP     409
#define STEP_F  0.1f
#define THR_F   0.01f

// GEMM tiling: 64x64 output tile, BK=16, 256 threads, 4x4 accum per thread.
#define BM  64
#define BN  64
#define BK  16
#define LDT 68   // padded LDS leading dim (+4 floats keeps b128 alignment, breaks bank stride)

__device__ __forceinline__ float soft_update(float oldv, float g) {
    float a = oldv + STEP_F * g;
    float m = fabsf(a) - THR_F;
    return m > 0.0f ? copysignf(m, a) : 0.0f;
}

// R = X - A*D    A:[BATCH,DICT]  D:[DICT,EXP_DIM]  X,R:[BATCH,EXP_DIM]
__global__ __launch_bounds__(256)
void gemm1_resid(const float* __restrict__ A, const float* __restrict__ D,
                 const float* __restrict__ X, float* __restrict__ R) {
    __shared__ float As[BK][LDT];
    __shared__ float Bs[BK][LDT];
    const int t    = threadIdx.x;
    const int row0 = blockIdx.y * BM;
    const int col0 = blockIdx.x * BN;
    const int tx = t & 15, ty = t >> 4;
    const int lr = t >> 2;           // 0..63 (tile row for A load)
    const int lk = (t & 3) << 2;     // 0,4,8,12 (k offset for A load)
    const int bkr = t >> 4;          // 0..15 (k row for B load)
    const int bn  = (t & 15) << 2;   // 0..60 (col offset for B load)

    float acc[4][4] = {};

    for (int k0 = 0; k0 < DICT; k0 += BK) {
        float4 av = *(const float4*)&A[(row0 + lr) * DICT + k0 + lk];
        float4 bv = *(const float4*)&D[(k0 + bkr) * EXP_DIM + col0 + bn];
        __syncthreads();
        As[lk + 0][lr] = av.x; As[lk + 1][lr] = av.y;
        As[lk + 2][lr] = av.z; As[lk + 3][lr] = av.w;
        *(float4*)&Bs[bkr][bn] = bv;
        __syncthreads();
#pragma unroll
        for (int k = 0; k < BK; ++k) {
            float4 a = *(const float4*)&As[k][ty << 2];
            float4 b = *(const float4*)&Bs[k][tx << 2];
            float avr[4] = {a.x, a.y, a.z, a.w};
            float bvr[4] = {b.x, b.y, b.z, b.w};
#pragma unroll
            for (int i = 0; i < 4; ++i)
#pragma unroll
                for (int j = 0; j < 4; ++j)
                    acc[i][j] += avr[i] * bvr[j];
        }
    }

#pragma unroll
    for (int i = 0; i < 4; ++i) {
        int r = row0 + (ty << 2) + i;
        int c = col0 + (tx << 2);
        float4 xv = *(const float4*)&X[r * EXP_DIM + c];
        float4 o;
        o.x = xv.x - acc[i][0];
        o.y = xv.y - acc[i][1];
        o.z = xv.z - acc[i][2];
        o.w = xv.w - acc[i][3];
        *(float4*)&R[r * EXP_DIM + c] = o;
    }
}

// A = soft(A + STEP * R*D^T)   R:[BATCH,EXP_DIM]  D:[DICT,EXP_DIM]  A:[BATCH,DICT]
__global__ __launch_bounds__(256)
void gemm2_update(const float* __restrict__ R, const float* __restrict__ D,
                  float* __restrict__ A) {
    __shared__ float As[BK][LDT];
    __shared__ float Bs[BK][LDT];
    const int t    = threadIdx.x;
    const int row0 = blockIdx.y * BM;
    const int col0 = blockIdx.x * BN;  // atom index tile
    const int tx = t & 15, ty = t >> 4;
    const int lr = t >> 2;
    const int lk = (t & 3) << 2;

    float acc[4][4] = {};

    for (int k0 = 0; k0 < EXP_DIM; k0 += BK) {
        float4 av = *(const float4*)&R[(row0 + lr) * EXP_DIM + k0 + lk];
        float4 bv = *(const float4*)&D[(col0 + lr) * EXP_DIM + k0 + lk];
        __syncthreads();
        As[lk + 0][lr] = av.x; As[lk + 1][lr] = av.y;
        As[lk + 2][lr] = av.z; As[lk + 3][lr] = av.w;
        Bs[lk + 0][lr] = bv.x; Bs[lk + 1][lr] = bv.y;
        Bs[lk + 2][lr] = bv.z; Bs[lk + 3][lr] = bv.w;
        __syncthreads();
#pragma unroll
        for (int k = 0; k < BK; ++k) {
            float4 a = *(const float4*)&As[k][ty << 2];
            float4 b = *(const float4*)&Bs[k][tx << 2];
            float avr[4] = {a.x, a.y, a.z, a.w};
            float bvr[4] = {b.x, b.y, b.z, b.w};
#pragma unroll
            for (int i = 0; i < 4; ++i)
#pragma unroll
                for (int j = 0; j < 4; ++j)
                    acc[i][j] += avr[i] * bvr[j];
        }
    }

#pragma unroll
    for (int i = 0; i < 4; ++i) {
        int r = row0 + (ty << 2) + i;
        size_t off = (size_t)r * DICT + col0 + (tx << 2);
        float4* p = (float4*)&A[off];
        float4 oldv = *p;
        float4 o;
        o.x = soft_update(oldv.x, acc[i][0]);
        o.y = soft_update(oldv.y, acc[i][1]);
        o.z = soft_update(oldv.z, acc[i][2]);
        o.w = soft_update(oldv.w, acc[i][3]);
        *p = o;
    }
}

// In-place top-KSP by |value| per row of A[BATCH,DICT].
// Exact: MSB-first radix select on abs bit patterns (order of abs-float == order
// of its uint bits), stable-by-index among equals (matches jax.lax.top_k ties).
__global__ __launch_bounds__(256)
void topk_kernel(float* __restrict__ A) {
    const int row = blockIdx.x;
    float* a = A + (size_t)row * DICT;
    __shared__ unsigned int sb[DICT];
    __shared__ unsigned int hist[256];
    __shared__ unsigned int s_bin, s_need;
    const int t = threadIdx.x;

#pragma unroll
    for (int i = 0; i < DICT / 256; ++i) {
        int j = t + 256 * i;
        sb[j] = __float_as_uint(a[j]) & 0x7fffffffu;
    }

    unsigned int prefix = 0, needed = KSP;
    for (int shift = 24; shift >= 0; shift -= 8) {
        __syncthreads();
        hist[t] = 0;
        __syncthreads();
        unsigned int hmask = (shift == 24) ? 0u : (0xffffffffu << (shift + 8));
        for (int i = 0; i < DICT / 256; ++i) {
            unsigned int b = sb[t + 256 * i];
            if ((b & hmask) == prefix)
                atomicAdd(&hist[(b >> shift) & 0xffu], 1u);
        }
        __syncthreads();
        if (t == 0) {
            unsigned int cum = 0;
            for (int bin = 255; bin >= 0; --bin) {
                unsigned int h = hist[bin];
                if (cum + h >= needed) { s_bin = (unsigned int)bin; s_need = needed - cum; break; }
                cum += h;
            }
        }
        __syncthreads();
        prefix |= s_bin << shift;
        needed = s_need;
    }

    // hist still holds the final-round histogram; E = #elements exactly == prefix
    unsigned int E = hist[prefix & 0xffu];
    bool simple = (E == needed) || (prefix == 0);
    // prefix==0: boundary is zero-magnitude; keeping "extra" zeros writes 0 -> harmless.
    if (!simple) {
        // Rare exact-tie at nonzero magnitude: stable-select first `needed` by index.
        if (t == 0) {
            unsigned int cnt = 0;
            for (int j = 0; j < DICT; ++j) {
                if (sb[j] == prefix) {
                    if (cnt < needed) sb[j] |= 0x80000000u;
                    ++cnt;
                }
            }
        }
        __syncthreads();
    }

    for (int i = 0; i < DICT / 256; ++i) {
        int j = t + 256 * i;
        unsigned int b = sb[j];
        bool keep = simple ? (b >= prefix)
                           : (((b & 0x7fffffffu) > prefix) || (b >> 31));
        float v = a[j];
        a[j] = keep ? v : 0.0f;
    }
}

extern "C" void kernel_launch(void* const* d_in, const int* in_sizes, int n_in,
                              void* d_out, int out_size, void* d_ws, size_t ws_size,
                              hipStream_t stream) {
    const float* X = (const float*)d_in[0];   // [8192,1024]
    const float* D = (const float*)d_in[1];   // [4096,1024]
    float* A = (float*)d_out;                 // [8192,4096] alpha, iterated in place
    float* R = (float*)d_ws;                  // [8192,1024] residual scratch (33.5 MB)

    hipMemsetAsync(A, 0, (size_t)BATCH * DICT * sizeof(float), stream);

    dim3 blk(256);
    dim3 g1(EXP_DIM / BN, BATCH / BM);  // 16 x 128
    dim3 g2(DICT / BN,    BATCH / BM);  // 64 x 128

    for (int it = 0; it < NIT; ++it) {
        // iter 0: A==0 -> R = X exactly (matches reference's first step)
        hipLaunchKernelGGL(gemm1_resid, g1, blk, 0, stream, A, D, X, R);
        hipLaunchKernelGGL(gemm2_update, g2, blk, 0, stream, R, D, A);
    }
    hipLaunchKernelGGL(topk_kernel, dim3(BATCH), blk, 0, stream, A);
}